// Round 10
// baseline (567.841 us; speedup 1.0000x reference)
//
#include <hip/hip_runtime.h>
#include <hip/hip_bf16.h>

#define B_SZ 16384
#define D_SZ 1024
#define H_SZ 2048
#define C_SZ 128
#define T_STEPS 20

typedef __attribute__((ext_vector_type(4))) float f32x4;
typedef __attribute__((ext_vector_type(16))) float f32x16;
typedef __attribute__((ext_vector_type(8))) short bf16x8;

__device__ __forceinline__ unsigned int lif_mask(float i1) {
    float u = 0.0f;
    unsigned int m = 0;
    #pragma unroll
    for (int t = 0; t < T_STEPS; ++t) {
        u = __fadd_rn(__fmul_rn(0.9f, u), i1);   // match np: separate mul, add
        if (u >= 1.0f) { m |= (1u << t); u = 0.0f; }
    }
    return m;
}

// ---------------- generic fp32 -> 2 bf16 planes splitter (RNE hi, RNE mid) ----------
__global__ void k_split2(const float* __restrict__ src, unsigned short* __restrict__ dst, int n) {
    int i = blockIdx.x * blockDim.x + threadIdx.x;   // float4 index
    float4 v = reinterpret_cast<const float4*>(src)[i];
    float f[4] = {v.x, v.y, v.z, v.w};
    unsigned short h[4], m[4];
    #pragma unroll
    for (int j = 0; j < 4; ++j) {
        __hip_bfloat16 hb = __float2bfloat16(f[j]);
        h[j] = __bfloat16_as_ushort(hb);
        m[j] = __bfloat16_as_ushort(__float2bfloat16(f[j] - __bfloat162float(hb)));
    }
    reinterpret_cast<ushort4*>(dst)[i] = make_ushort4(h[0], h[1], h[2], h[3]);
    reinterpret_cast<ushort4*>(dst + n)[i] = make_ushort4(m[0], m[1], m[2], m[3]);
}

// ---------------- pre-permute W2 planes into MFMA fragment order (K2, 8-nt) ----------
// dst u16 layout: [kt(64)][s(2)][nt(8)][lane(64)][8]
__global__ void k_w2frag8(const unsigned short* __restrict__ W2p, unsigned short* __restrict__ W2f) {
    int idx = blockIdx.x * blockDim.x + threadIdx.x;   // 0..65535
    int lane = idx & 63;
    int nt   = (idx >> 6) & 7;
    int s    = (idx >> 9) & 1;
    int kt   = idx >> 10;
    int c = nt * 16 + (lane & 15);
    int h = kt * 32 + (lane >> 4) * 8;
    uint4 v = *reinterpret_cast<const uint4*>(W2p + ((size_t)s * C_SZ + c) * H_SZ + h);
    *reinterpret_cast<uint4*>(W2f + (size_t)idx * 8) = v;
}

// ---------------- pre-permute W1 planes into 32x32 MFMA fragment order (K1) ----------
// dst u16 layout: [p(16)][kt(64)][m(4)][s(2)][lane(64)][8]   (idx == run index)
// value = w1s[s][h = p*128 + m*32 + (lane&31)][k = kt*16 + (lane>>5)*8 .. +7]
__global__ void k_w1frag32(const unsigned short* __restrict__ w1s, unsigned short* __restrict__ w1f) {
    int idx = blockIdx.x * blockDim.x + threadIdx.x;   // 0..524287
    int lane = idx & 63;
    int s    = (idx >> 6) & 1;
    int m    = (idx >> 7) & 3;
    int kt   = (idx >> 9) & 63;
    int p    = idx >> 15;
    int h = p * 128 + m * 32 + (lane & 31);
    int k = kt * 16 + (lane >> 5) * 8;
    uint4 v = *reinterpret_cast<const uint4*>(w1s + ((size_t)s * H_SZ + h) * D_SZ + k);
    *reinterpret_cast<uint4*>(w1f + (size_t)idx * 8) = v;
}

// ---------------- fused split + 32x32 frag-permute of x -----------------------------
// dst u16 layout: [bg(256)][kt(64)][n(2)][s(2)][lane(64)][8]
// value = splitplane_s( x[b = bg*64 + n*32 + (lane&31)][k = kt*16 + (lane>>5)*8 .. +7] )
__global__ void k_xfrag32(const float* __restrict__ x, unsigned short* __restrict__ xf) {
    int idx = blockIdx.x * blockDim.x + threadIdx.x;   // 0..2097151  (b, k8)
    int k8 = idx & 127;          // 8-float run within row
    int b  = idx >> 7;
    int kt = k8 >> 1;
    int kj = k8 & 1;             // k-group = lane>>5
    int l31 = b & 31;
    int n   = (b >> 5) & 1;
    int bg  = b >> 6;
    int lane = kj * 32 + l31;
    const float* src = x + (size_t)b * D_SZ + k8 * 8;
    float4 v0 = *reinterpret_cast<const float4*>(src);
    float4 v1 = *reinterpret_cast<const float4*>(src + 4);
    float f[8] = {v0.x, v0.y, v0.z, v0.w, v1.x, v1.y, v1.z, v1.w};
    unsigned short h[8], m[8];
    #pragma unroll
    for (int j = 0; j < 8; ++j) {
        __hip_bfloat16 hb = __float2bfloat16(f[j]);
        h[j] = __bfloat16_as_ushort(hb);
        m[j] = __bfloat16_as_ushort(__float2bfloat16(f[j] - __bfloat162float(hb)));
    }
    // run offset: (((bg*64 + kt)*2 + n)*2 + s)*64 + lane
    size_t r0 = ((((size_t)bg * 64 + kt) * 2 + n) * 2 + 0) * 64 + lane;
    size_t r1 = r0 + 64;   // s = 1
    *reinterpret_cast<ushort4*>(xf + r0 * 8)     = make_ushort4(h[0], h[1], h[2], h[3]);
    *reinterpret_cast<ushort4*>(xf + r0 * 8 + 4) = make_ushort4(h[4], h[5], h[6], h[7]);
    *reinterpret_cast<ushort4*>(xf + r1 * 8)     = make_ushort4(m[0], m[1], m[2], m[3]);
    *reinterpret_cast<ushort4*>(xf + r1 * 8 + 4) = make_ushort4(m[4], m[5], m[6], m[7]);
}

// ---------------- K1: LDS-free, barrier-free 32x32-MFMA frag-GEMM + fused LIF --------
// Grid 2048 x 256 thr (4 waves; wave = 64h x 64b quadrant; 2x2 MFMAs of 32x32).
// Per kt(K=16): 8 loads (all 13-bit-immediate offsets off 2 base ptrs) + 12 MFMAs.
// A/B both self-built with row/col = lane&31, k = (lane>>5)*8+j (symmetric -> any
// common k-permutation cancels). D: col=lane&31, row=(reg&3)+8*(reg>>2)+4*(lane>>5).
__global__ __launch_bounds__(256, 2) void k_gemm1_frag(
    const unsigned short* __restrict__ xf,    // [bg][kt][n][s][lane][8]
    const unsigned short* __restrict__ w1f,   // [p][kt][m][s][lane][8]
    const float* __restrict__ b1,
    unsigned short* __restrict__ M16,
    unsigned char* __restrict__ M4,
    unsigned int* __restrict__ spike_count)
{
    const int tid  = threadIdx.x;
    const int wv   = tid >> 6;
    const int lane = tid & 63;
    const int l31  = lane & 31;
    const int g5   = lane >> 5;
    const int wr   = wv >> 1;      // h half (64)
    const int wc   = wv & 1;       // b half (64)

    const int wg    = blockIdx.x;
    const int xcd   = wg & 7;
    const int local = wg >> 3;
    const int sc    = local >> 4;
    const int sl    = local & 15;
    const int b_panel = xcd * 16 + (sc >> 2) * 4 + (sl >> 2);
    const int h_idx   = (sc & 3) * 4 + (sl & 3);
    const int hb0 = h_idx * 128;
    const int bb0 = b_panel * 128;

    f32x16 acc[2][2];
    #pragma unroll
    for (int i = 0; i < 2; ++i)
        #pragma unroll
        for (int j = 0; j < 2; ++j)
            #pragma unroll
            for (int e = 0; e < 16; ++e)
                acc[i][j][e] = 0.f;

    // A: strides (u16): lane-run 8, s 512, m 1024, kt 4096, p 262144
    const unsigned short* Ap = w1f + (size_t)h_idx * 262144 + (size_t)(wr * 2) * 1024 + (size_t)lane * 8;
    // B: strides (u16): s 512, n 1024, kt 2048, bg 131072
    const unsigned short* Bp = xf + (size_t)(b_panel * 2 + wc) * 131072 + (size_t)lane * 8;

    #pragma unroll 2
    for (int kt = 0; kt < 64; ++kt) {
        bf16x8 Aa[2][2], Bb[2][2];   // [s][m'], [s][n]
        #pragma unroll
        for (int mm = 0; mm < 2; ++mm)
            #pragma unroll
            for (int s = 0; s < 2; ++s)
                Aa[s][mm] = *reinterpret_cast<const bf16x8*>(Ap + mm * 1024 + s * 512);
        #pragma unroll
        for (int n = 0; n < 2; ++n)
            #pragma unroll
            for (int s = 0; s < 2; ++s)
                Bb[s][n] = *reinterpret_cast<const bf16x8*>(Bp + n * 1024 + s * 512);
        #pragma unroll
        for (int mm = 0; mm < 2; ++mm)
            #pragma unroll
            for (int n = 0; n < 2; ++n) {
                acc[mm][n] = __builtin_amdgcn_mfma_f32_32x32x16_bf16(Aa[0][mm], Bb[0][n], acc[mm][n], 0, 0, 0);
                acc[mm][n] = __builtin_amdgcn_mfma_f32_32x32x16_bf16(Aa[0][mm], Bb[1][n], acc[mm][n], 0, 0, 0);
                acc[mm][n] = __builtin_amdgcn_mfma_f32_32x32x16_bf16(Aa[1][mm], Bb[0][n], acc[mm][n], 0, 0, 0);
            }
        Ap += 4096;
        Bp += 2048;
    }

    // epilogue: reg j -> h row = (j&3) + 8*(j>>2) + 4*g5; col = l31 (b)
    int spikes = 0;
    #pragma unroll
    for (int mm = 0; mm < 2; ++mm) {
        #pragma unroll
        for (int n = 0; n < 2; ++n) {
            const int bcol = bb0 + wc * 64 + n * 32 + l31;
            #pragma unroll
            for (int q = 0; q < 4; ++q) {
                const int h0l = hb0 + wr * 64 + mm * 32 + q * 8 + g5 * 4;
                float4 bias = *reinterpret_cast<const float4*>(b1 + h0l);
                unsigned mk0 = lif_mask(acc[mm][n][4 * q + 0] + bias.x);
                unsigned mk1 = lif_mask(acc[mm][n][4 * q + 1] + bias.y);
                unsigned mk2 = lif_mask(acc[mm][n][4 * q + 2] + bias.z);
                unsigned mk3 = lif_mask(acc[mm][n][4 * q + 3] + bias.w);
                spikes += __popc(mk0) + __popc(mk1) + __popc(mk2) + __popc(mk3);
                *reinterpret_cast<uint2*>(M16 + (size_t)bcol * H_SZ + h0l) =
                    make_uint2((mk0 & 0xffffu) | (mk1 << 16),
                               (mk2 & 0xffffu) | (mk3 << 16));
                *reinterpret_cast<unsigned int*>(M4 + (size_t)bcol * H_SZ + h0l) =
                    (mk0 >> 16) | ((mk1 >> 16) << 8) | ((mk2 >> 16) << 16) | ((mk3 >> 16) << 24);
            }
        }
    }
    #pragma unroll
    for (int off = 32; off > 0; off >>= 1)
        spikes += __shfl_down(spikes, off);
    if (lane == 0)
        atomicAdd(spike_count, (unsigned int)spikes);
}

// ---------------- K2: layer 2, LDS-free main loop, 4 waves x 8 n-tiles (unchanged) ----
__global__ __launch_bounds__(256, 2) void k_layer2_mfma(
    const unsigned short* __restrict__ M16,
    const unsigned char* __restrict__ M4,
    const unsigned short* __restrict__ W2f,   // frag-ordered [kt][s][nt8][lane][8]
    const float* __restrict__ b2,
    float* __restrict__ out)
{
    __shared__ __align__(16) float smem[5700];   // 16b x 16c (pad 17) x 21t
    const int tid  = threadIdx.x;
    const int tg   = tid >> 6;        // wave = t-group: t in [tg*5, tg*5+5)
    const int lane = tid & 63;
    const int l15  = lane & 15;
    const int g    = lane >> 4;
    const int b0   = blockIdx.x * 16;
    const int t0   = tg * 5;

    f32x4 acc[8][5];
    #pragma unroll
    for (int n = 0; n < 8; ++n)
        #pragma unroll
        for (int t = 0; t < 5; ++t)
            acc[n][t] = (f32x4){0.f, 0.f, 0.f, 0.f};

    const unsigned short* m16row = M16 + (size_t)(b0 + l15) * H_SZ + g * 8;
    const unsigned char*  m4row  = M4  + (size_t)(b0 + l15) * H_SZ + g * 8;
    const unsigned short* fbase  = W2f + (size_t)lane * 8;

    for (int kt = 0; kt < 64; ++kt) {
        uint4 w16 = *reinterpret_cast<const uint4*>(m16row + kt * 32);
        uint2 w4 = make_uint2(0u, 0u);
        if (tg == 3)
            w4 = *reinterpret_cast<const uint2*>(m4row + kt * 32);

        union { bf16x8 v; unsigned int u[4]; } A[5];
        #pragma unroll
        for (int tl = 0; tl < 5; ++tl) {
            const int t = t0 + tl;
            if (t < 16) {
                A[tl].u[0] = ((w16.x >> t) & 0x10001u) * 0x3F80u;
                A[tl].u[1] = ((w16.y >> t) & 0x10001u) * 0x3F80u;
                A[tl].u[2] = ((w16.z >> t) & 0x10001u) * 0x3F80u;
                A[tl].u[3] = ((w16.w >> t) & 0x10001u) * 0x3F80u;
            } else {
                const int tt = t - 16;
                unsigned x0 = (w4.x >> tt)        & 0x101u;
                unsigned x1 = (w4.x >> (16 + tt)) & 0x101u;
                unsigned x2 = (w4.y >> tt)        & 0x101u;
                unsigned x3 = (w4.y >> (16 + tt)) & 0x101u;
                A[tl].u[0] = ((x0 * 0x0101u) & 0x10001u) * 0x3F80u;
                A[tl].u[1] = ((x1 * 0x0101u) & 0x10001u) * 0x3F80u;
                A[tl].u[2] = ((x2 * 0x0101u) & 0x10001u) * 0x3F80u;
                A[tl].u[3] = ((x3 * 0x0101u) & 0x10001u) * 0x3F80u;
            }
        }

        const unsigned short* fk = fbase + (size_t)kt * 8192;
        #pragma unroll
        for (int s = 0; s < 2; ++s) {
            bf16x8 Bf[8];
            #pragma unroll
            for (int nt = 0; nt < 8; ++nt)
                Bf[nt] = *reinterpret_cast<const bf16x8*>(fk + s * 4096 + nt * 512);
            #pragma unroll
            for (int tl = 0; tl < 5; ++tl)
                #pragma unroll
                for (int nt = 0; nt < 8; ++nt)
                    acc[nt][tl] = __builtin_amdgcn_mfma_f32_16x16x32_bf16(
                        A[tl].v, Bf[nt], acc[nt][tl], 0, 0, 0);
        }
    }

    #pragma unroll
    for (int q = 0; q < 8; ++q) {
        __syncthreads();
        #pragma unroll
        for (int tl = 0; tl < 5; ++tl)
            #pragma unroll
            for (int j = 0; j < 4; ++j)
                smem[((g * 4 + j) * 17 + l15) * 21 + (t0 + tl)] = acc[q][tl][j];
        __syncthreads();
        {
            const int bl  = tid >> 4;     // 0..15
            const int c16 = tid & 15;
            const int c   = q * 16 + c16;
            const float bias = b2[c];
            float u2 = 0.0f; int cnt = 0;
            #pragma unroll
            for (int t = 0; t < T_STEPS; ++t) {
                float X = smem[(bl * 17 + c16) * 21 + t] + bias;
                u2 = __fadd_rn(__fmul_rn(0.9f, u2), X);
                if (u2 >= 1.0f) { cnt++; u2 = 0.0f; }
            }
            out[(size_t)(b0 + bl) * C_SZ + c] = (float)cnt / 20.0f;
        }
    }
}

// ---------------- K3: mean_spikes = total / (B * T) ----------------
__global__ void k_finalize(const unsigned int* __restrict__ spike_count, float* __restrict__ out) {
    out[(size_t)B_SZ * C_SZ] = (float)(*spike_count) / (float)((size_t)B_SZ * T_STEPS);
}

extern "C" void kernel_launch(void* const* d_in, const int* in_sizes, int n_in,
                              void* d_out, int out_size, void* d_ws, size_t ws_size,
                              hipStream_t stream) {
    const float* x  = (const float*)d_in[0];
    const float* W1 = (const float*)d_in[1];
    const float* b1 = (const float*)d_in[2];
    const float* W2 = (const float*)d_in[3];
    const float* b2 = (const float*)d_in[4];
    float* out = (float*)d_out;

    char* ws = (char*)d_ws;
    const size_t m16_b = (size_t)B_SZ * H_SZ * 2;        // 67.1 MB
    const size_t m4_b  = (size_t)B_SZ * H_SZ;            // 33.6 MB
    const size_t w1s_b = (size_t)2 * H_SZ * D_SZ * 2;    // 8.4 MB
    const size_t w2p_b = (size_t)2 * C_SZ * H_SZ * 2;    // 1.05 MB
    const size_t xf_b  = (size_t)2 * B_SZ * D_SZ * 2;    // 67.1 MB
    const size_t w1f_b = w1s_b;                          // 8.4 MB

    size_t off = 0;
    unsigned short* M16 = (unsigned short*)(ws + off); off += m16_b;
    unsigned char*  M4  = (unsigned char*)(ws + off);  off += m4_b;
    unsigned short* w1s = (unsigned short*)(ws + off); off += w1s_b;
    unsigned short* W2p = (unsigned short*)(ws + off); off += w2p_b;
    unsigned short* W2f = (unsigned short*)(ws + off); off += w2p_b;
    unsigned int* counter = (unsigned int*)(ws + off); off += 256;
    unsigned short* xf  = (unsigned short*)(ws + off); off += xf_b;
    unsigned short* w1f = (unsigned short*)(ws + off); off += w1f_b;

    hipMemsetAsync(counter, 0, sizeof(unsigned int), stream);

    k_split2<<<(H_SZ * D_SZ) / 1024, 256, 0, stream>>>(W1, w1s, H_SZ * D_SZ);
    k_split2<<<(C_SZ * H_SZ) / 1024, 256, 0, stream>>>(W2, W2p, C_SZ * H_SZ);
    k_w2frag8<<<256, 256, 0, stream>>>(W2p, W2f);
    k_w1frag32<<<2048, 256, 0, stream>>>(w1s, w1f);
    k_xfrag32<<<8192, 256, 0, stream>>>(x, xf);

    k_gemm1_frag<<<2048, 256, 0, stream>>>(xf, w1f, b1, M16, M4, counter);

    k_layer2_mfma<<<B_SZ / 16, 256, 0, stream>>>(M16, M4, W2f, b2, out);

    k_finalize<<<1, 1, 0, stream>>>(counter, out);
}

// Round 12
// 307.328 us; speedup vs baseline: 1.8477x; 1.8477x over previous
//
#include <hip/hip_runtime.h>
#include <hip/hip_fp8.h>

#define B_SZ 16384
#define D_SZ 1024
#define H_SZ 2048
#define C_SZ 128
#define T_STEPS 20

typedef __attribute__((ext_vector_type(4))) float f32x4;

__device__ __forceinline__ unsigned int lif_mask(float i1) {
    float u = 0.0f;
    unsigned int m = 0;
    #pragma unroll
    for (int t = 0; t < T_STEPS; ++t) {
        u = __fadd_rn(__fmul_rn(0.9f, u), i1);   // match np: separate mul, add
        if (u >= 1.0f) { m |= (1u << t); u = 0.0f; }
    }
    return m;
}

__device__ __forceinline__ unsigned char to_fp8(float f) {
    __hip_fp8_e4m3 q(f);
    return (unsigned char)q.__x;
}

__device__ __forceinline__ long pk64(unsigned int lo, unsigned int hi) {
    return (long)(((unsigned long long)hi << 32) | (unsigned long long)lo);
}

// ---------------- W1 -> fp8 frags: [p(16)][kt(32)][wr(2)][mp(2)][lane(64)][16B] ------
// byte j of 16B run: m' = mp*2 + (j>>3); h = p*128 + wr*64 + m'*16 + (lane&15);
// k = kt*32 + (lane>>4)*8 + (j&7). value = fp8(32 * W1[h][k]).
// thread = one 8-byte half-run. 262144 threads exactly.
__global__ void k_w1frag8(const float* __restrict__ W1, unsigned char* __restrict__ w1f) {
    int idx = blockIdx.x * blockDim.x + threadIdx.x;   // 0..262143
    int halfsel = idx & 1;
    int lane = (idx >> 1) & 63;
    int mp   = (idx >> 7) & 1;
    int wr   = (idx >> 8) & 1;
    int kt   = (idx >> 9) & 31;
    int p    = idx >> 14;
    int h = p * 128 + wr * 64 + (mp * 2 + halfsel) * 16 + (lane & 15);
    int k = kt * 32 + (lane >> 4) * 8;
    const float* src = W1 + (size_t)h * D_SZ + k;
    float4 v0 = *reinterpret_cast<const float4*>(src);
    float4 v1 = *reinterpret_cast<const float4*>(src + 4);
    float f[8] = {v0.x, v0.y, v0.z, v0.w, v1.x, v1.y, v1.z, v1.w};
    union { unsigned char b[8]; uint2 u; } q;
    #pragma unroll
    for (int j = 0; j < 8; ++j) q.b[j] = to_fp8(32.0f * f[j]);
    size_t off = (size_t)p * 131072 + (size_t)kt * 4096 + wr * 2048 + mp * 1024
               + lane * 16 + halfsel * 8;
    *reinterpret_cast<uint2*>(w1f + off) = q.u;
}

// ---------------- x -> fp8 frags: [bg(256)][kt(32)][np(2)][lane(64)][16B] ------------
// byte j: n = np*2 + (j>>3); b = bg*64 + n*16 + (lane&15); k = kt*32+(lane>>4)*8+(j&7).
// 2097152 threads exactly.
__global__ void k_xfrag8(const float* __restrict__ x, unsigned char* __restrict__ xf) {
    int idx = blockIdx.x * blockDim.x + threadIdx.x;   // 0..2097151
    int halfsel = idx & 1;
    int lane = (idx >> 1) & 63;
    int np   = (idx >> 7) & 1;
    int kt   = (idx >> 8) & 31;
    int bg   = idx >> 13;
    int b = bg * 64 + (np * 2 + halfsel) * 16 + (lane & 15);
    int k = kt * 32 + (lane >> 4) * 8;
    const float* src = x + (size_t)b * D_SZ + k;
    float4 v0 = *reinterpret_cast<const float4*>(src);
    float4 v1 = *reinterpret_cast<const float4*>(src + 4);
    float f[8] = {v0.x, v0.y, v0.z, v0.w, v1.x, v1.y, v1.z, v1.w};
    union { unsigned char b[8]; uint2 u; } q;
    #pragma unroll
    for (int j = 0; j < 8; ++j) q.b[j] = to_fp8(f[j]);
    size_t off = (size_t)bg * 65536 + (size_t)kt * 2048 + np * 1024
               + lane * 16 + halfsel * 8;
    *reinterpret_cast<uint2*>(xf + off) = q.u;
}

// ---------------- W2 -> fp8 frags: [kt(64)][ntp(4)][lane(64)][16B], k-perm baked -----
// byte j: nt = ntp*2+(j>>3); c = nt*16+(lane&15); h = kt*32+(lane>>4)*8+perm[j&7];
// perm = {0,2,1,3,4,6,5,7}  (matches K2's in-register A byte order).
// 16384 threads EXACTLY (round-11 bug: 32768 threads overran w2f8 into counter).
__global__ void k_w2frag8(const float* __restrict__ W2, unsigned char* __restrict__ w2f) {
    const int perm[8] = {0, 2, 1, 3, 4, 6, 5, 7};
    int idx = blockIdx.x * blockDim.x + threadIdx.x;   // 0..16383
    int lane = idx & 63;
    int ntp  = (idx >> 6) & 3;
    int kt   = idx >> 8;                               // 0..63
    union { unsigned char b[16]; uint4 u; } q;
    #pragma unroll
    for (int half = 0; half < 2; ++half) {
        int c = (ntp * 2 + half) * 16 + (lane & 15);
        const float* src = W2 + (size_t)c * H_SZ + kt * 32 + (lane >> 4) * 8;
        float4 v0 = *reinterpret_cast<const float4*>(src);
        float4 v1 = *reinterpret_cast<const float4*>(src + 4);
        float f[8] = {v0.x, v0.y, v0.z, v0.w, v1.x, v1.y, v1.z, v1.w};
        #pragma unroll
        for (int j = 0; j < 8; ++j)
            q.b[half * 8 + j] = to_fp8(32.0f * f[perm[j]]);
    }
    *reinterpret_cast<uint4*>(w2f + (size_t)idx * 16) = q.u;
}

// ---------------- K1: LDS-free fp8 frag-GEMM + fused LIF -----------------------------
// Grid 2048 x 256 thr (4 waves, 64x64 out each). Per kt(K=32): 4 dwordx4 loads
// + 16 mfma_f32_16x16x32_fp8_fp8. Epilogue: i1 = acc/32 + b1 -> LIF -> masks.
__global__ __launch_bounds__(256, 2) void k_gemm1_fp8(
    const unsigned char* __restrict__ xf,
    const unsigned char* __restrict__ w1f,
    const float* __restrict__ b1,
    unsigned short* __restrict__ M16,
    unsigned char* __restrict__ M4,
    unsigned int* __restrict__ spike_count)
{
    const int tid  = threadIdx.x;
    const int wv   = tid >> 6;
    const int lane = tid & 63;
    const int l15  = lane & 15;
    const int g    = lane >> 4;
    const int wr   = wv >> 1;
    const int wc   = wv & 1;

    const int wg    = blockIdx.x;
    const int xcd   = wg & 7;
    const int local = wg >> 3;
    const int sc    = local >> 4;
    const int sl    = local & 15;
    const int b_panel = xcd * 16 + (sc >> 2) * 4 + (sl >> 2);
    const int h_idx   = (sc & 3) * 4 + (sl & 3);
    const int hb0 = h_idx * 128;
    const int bb0 = b_panel * 128;

    f32x4 acc[4][4];
    #pragma unroll
    for (int i = 0; i < 4; ++i)
        #pragma unroll
        for (int j = 0; j < 4; ++j)
            acc[i][j] = (f32x4){0.f, 0.f, 0.f, 0.f};

    const unsigned char* Ap = w1f + (size_t)h_idx * 131072 + wr * 2048 + lane * 16;
    const unsigned char* Bp = xf + (size_t)(b_panel * 2 + wc) * 65536 + lane * 16;

    #pragma unroll 2
    for (int kt = 0; kt < 32; ++kt) {
        uint4 a0 = *reinterpret_cast<const uint4*>(Ap);
        uint4 a1 = *reinterpret_cast<const uint4*>(Ap + 1024);
        uint4 c0 = *reinterpret_cast<const uint4*>(Bp);
        uint4 c1 = *reinterpret_cast<const uint4*>(Bp + 1024);
        long A[4], Bq[4];
        A[0] = pk64(a0.x, a0.y); A[1] = pk64(a0.z, a0.w);
        A[2] = pk64(a1.x, a1.y); A[3] = pk64(a1.z, a1.w);
        Bq[0] = pk64(c0.x, c0.y); Bq[1] = pk64(c0.z, c0.w);
        Bq[2] = pk64(c1.x, c1.y); Bq[3] = pk64(c1.z, c1.w);
        #pragma unroll
        for (int m = 0; m < 4; ++m)
            #pragma unroll
            for (int n = 0; n < 4; ++n)
                acc[m][n] = __builtin_amdgcn_mfma_f32_16x16x32_fp8_fp8(
                    A[m], Bq[n], acc[m][n], 0, 0, 0);
        Ap += 4096;
        Bp += 2048;
    }

    int spikes = 0;
    #pragma unroll
    for (int m = 0; m < 4; ++m) {
        const int h0l = hb0 + wr * 64 + m * 16 + g * 4;
        float4 bias = *reinterpret_cast<const float4*>(b1 + h0l);
        #pragma unroll
        for (int n = 0; n < 4; ++n) {
            const int b = bb0 + wc * 64 + n * 16 + l15;
            unsigned mk0 = lif_mask(__fmul_rn(acc[m][n][0], 0.03125f) + bias.x);
            unsigned mk1 = lif_mask(__fmul_rn(acc[m][n][1], 0.03125f) + bias.y);
            unsigned mk2 = lif_mask(__fmul_rn(acc[m][n][2], 0.03125f) + bias.z);
            unsigned mk3 = lif_mask(__fmul_rn(acc[m][n][3], 0.03125f) + bias.w);
            spikes += __popc(mk0) + __popc(mk1) + __popc(mk2) + __popc(mk3);
            *reinterpret_cast<uint2*>(M16 + (size_t)b * H_SZ + h0l) =
                make_uint2((mk0 & 0xffffu) | (mk1 << 16),
                           (mk2 & 0xffffu) | (mk3 << 16));
            *reinterpret_cast<unsigned int*>(M4 + (size_t)b * H_SZ + h0l) =
                (mk0 >> 16) | ((mk1 >> 16) << 8) | ((mk2 >> 16) << 16) | ((mk3 >> 16) << 24);
        }
    }
    #pragma unroll
    for (int off = 32; off > 0; off >>= 1)
        spikes += __shfl_down(spikes, off);
    if (lane == 0)
        atomicAdd(spike_count, (unsigned int)spikes);
}

// ---------------- K2: layer 2 fp8, LDS-free main loop, 4 waves x 8 nt ----------------
// Wave tg owns 5 timesteps x 128 cols, 16 b-rows/block. Per kt: build 5 A frags
// (spike bits -> 0x38 bytes, k-perm {0,2,1,3,...} matching w2f8), 4 dwordx4 B loads,
// 40 mfma_f32_16x16x32_fp8_fp8. Epilogue: inj = acc/32, X = inj + b2, LIF.
__global__ __launch_bounds__(256, 2) void k_layer2_fp8(
    const unsigned short* __restrict__ M16,
    const unsigned char* __restrict__ M4,
    const unsigned char* __restrict__ W2f,
    const float* __restrict__ b2,
    float* __restrict__ out)
{
    __shared__ __align__(16) float smem[5700];   // 16b x 16c (pad 17) x 21t
    const int tid  = threadIdx.x;
    const int tg   = tid >> 6;        // wave = t-group: t in [tg*5, tg*5+5)
    const int lane = tid & 63;
    const int l15  = lane & 15;
    const int g    = lane >> 4;
    const int b0   = blockIdx.x * 16;
    const int t0   = tg * 5;

    f32x4 acc[8][5];
    #pragma unroll
    for (int n = 0; n < 8; ++n)
        #pragma unroll
        for (int t = 0; t < 5; ++t)
            acc[n][t] = (f32x4){0.f, 0.f, 0.f, 0.f};

    const unsigned short* m16row = M16 + (size_t)(b0 + l15) * H_SZ + g * 8;
    const unsigned char*  m4row  = M4  + (size_t)(b0 + l15) * H_SZ + g * 8;
    const unsigned char*  fbase  = W2f + (size_t)lane * 16;

    for (int kt = 0; kt < 64; ++kt) {
        uint4 w16 = *reinterpret_cast<const uint4*>(m16row + kt * 32);
        uint2 w4 = make_uint2(0u, 0u);
        if (tg == 3)
            w4 = *reinterpret_cast<const uint2*>(m4row + kt * 32);

        long A[5];
        #pragma unroll
        for (int tl = 0; tl < 5; ++tl) {
            const int t = t0 + tl;
            unsigned dw0, dw1;
            if (t < 16) {
                dw0 = ((w16.x >> t) & 0x10001u) * 0x38u | ((w16.y >> t) & 0x10001u) * 0x3800u;
                dw1 = ((w16.z >> t) & 0x10001u) * 0x38u | ((w16.w >> t) & 0x10001u) * 0x3800u;
            } else {
                const int tt = t - 16;
                unsigned f0 = ((w4.x >> tt) & 0x01010101u) * 0x38u;
                unsigned f1 = ((w4.y >> tt) & 0x01010101u) * 0x38u;
                dw0 = __builtin_amdgcn_perm(0u, f0, 0x03010200u);   // bytes [0,2,1,3]
                dw1 = __builtin_amdgcn_perm(0u, f1, 0x03010200u);
            }
            A[tl] = pk64(dw0, dw1);
        }

        const unsigned char* fk = fbase + (size_t)kt * 4096;
        long Bf[8];
        #pragma unroll
        for (int ntp = 0; ntp < 4; ++ntp) {
            uint4 v = *reinterpret_cast<const uint4*>(fk + ntp * 1024);
            Bf[ntp * 2]     = pk64(v.x, v.y);
            Bf[ntp * 2 + 1] = pk64(v.z, v.w);
        }
        #pragma unroll
        for (int tl = 0; tl < 5; ++tl)
            #pragma unroll
            for (int nt = 0; nt < 8; ++nt)
                acc[nt][tl] = __builtin_amdgcn_mfma_f32_16x16x32_fp8_fp8(
                    A[tl], Bf[nt], acc[nt][tl], 0, 0, 0);
    }

    // epilogue: 8 chunks of 16 cols; transpose through LDS, then LIF per (b,c)
    #pragma unroll
    for (int q = 0; q < 8; ++q) {
        __syncthreads();
        #pragma unroll
        for (int tl = 0; tl < 5; ++tl)
            #pragma unroll
            for (int j = 0; j < 4; ++j)
                smem[((g * 4 + j) * 17 + l15) * 21 + (t0 + tl)] = acc[q][tl][j];
        __syncthreads();
        {
            const int bl  = tid >> 4;     // 0..15
            const int c16 = tid & 15;
            const int c   = q * 16 + c16;
            const float bias = b2[c];
            float u2 = 0.0f; int cnt = 0;
            #pragma unroll
            for (int t = 0; t < T_STEPS; ++t) {
                float X = __fadd_rn(__fmul_rn(smem[(bl * 17 + c16) * 21 + t], 0.03125f), bias);
                u2 = __fadd_rn(__fmul_rn(0.9f, u2), X);
                if (u2 >= 1.0f) { cnt++; u2 = 0.0f; }
            }
            out[(size_t)(b0 + bl) * C_SZ + c] = (float)cnt / 20.0f;
        }
    }
}

// ---------------- K3: mean_spikes = total / (B * T) ----------------
__global__ void k_finalize(const unsigned int* __restrict__ spike_count, float* __restrict__ out) {
    out[(size_t)B_SZ * C_SZ] = (float)(*spike_count) / (float)((size_t)B_SZ * T_STEPS);
}

extern "C" void kernel_launch(void* const* d_in, const int* in_sizes, int n_in,
                              void* d_out, int out_size, void* d_ws, size_t ws_size,
                              hipStream_t stream) {
    const float* x  = (const float*)d_in[0];
    const float* W1 = (const float*)d_in[1];
    const float* b1 = (const float*)d_in[2];
    const float* W2 = (const float*)d_in[3];
    const float* b2 = (const float*)d_in[4];
    float* out = (float*)d_out;

    char* ws = (char*)d_ws;
    const size_t m16_b  = (size_t)B_SZ * H_SZ * 2;   // 67.1 MB
    const size_t m4_b   = (size_t)B_SZ * H_SZ;       // 33.6 MB
    const size_t xf8_b  = (size_t)B_SZ * D_SZ;       // 16.8 MB
    const size_t w1f8_b = (size_t)H_SZ * D_SZ;       //  2.1 MB
    const size_t w2f8_b = (size_t)C_SZ * H_SZ;       //  0.26 MB

    size_t off = 0;
    unsigned short* M16  = (unsigned short*)(ws + off); off += m16_b;
    unsigned char*  M4   = (unsigned char*)(ws + off);  off += m4_b;
    unsigned char*  xf8  = (unsigned char*)(ws + off);  off += xf8_b;
    unsigned char*  w1f8 = (unsigned char*)(ws + off);  off += w1f8_b;
    unsigned char*  w2f8 = (unsigned char*)(ws + off);  off += w2f8_b;
    unsigned int* counter = (unsigned int*)(ws + off);  off += 256;

    hipMemsetAsync(counter, 0, sizeof(unsigned int), stream);

    k_w1frag8<<<1024, 256, 0, stream>>>(W1, w1f8);
    k_w2frag8<<<64, 256, 0, stream>>>(W2, w2f8);     // 16384 threads EXACT (bugfix)
    k_xfrag8<<<8192, 256, 0, stream>>>(x, xf8);

    k_gemm1_fp8<<<2048, 256, 0, stream>>>(xf8, w1f8, b1, M16, M4, counter);

    k_layer2_fp8<<<B_SZ / 16, 256, 0, stream>>>(M16, M4, w2f8, b2, out);

    k_finalize<<<1, 1, 0, stream>>>(counter, out);
}

// Round 13
// 286.581 us; speedup vs baseline: 1.9814x; 1.0724x over previous
//
#include <hip/hip_runtime.h>
#include <hip/hip_fp8.h>

#define B_SZ 16384
#define D_SZ 1024
#define H_SZ 2048
#define C_SZ 128
#define T_STEPS 20

typedef __attribute__((ext_vector_type(4))) float f32x4;

__device__ __forceinline__ unsigned char to_fp8(float f) {
    __hip_fp8_e4m3 q(f);
    return (unsigned char)q.__x;
}

__device__ __forceinline__ long pk64(unsigned int lo, unsigned int hi) {
    return (long)(((unsigned long long)hi << 32) | (unsigned long long)lo);
}

// ---------------- W1 -> fp8 frags: [p(16)][kt(32)][wr(2)][mp(2)][lane(64)][16B] ------
__global__ void k_w1frag8(const float* __restrict__ W1, unsigned char* __restrict__ w1f) {
    int idx = blockIdx.x * blockDim.x + threadIdx.x;   // 0..262143
    int halfsel = idx & 1;
    int lane = (idx >> 1) & 63;
    int mp   = (idx >> 7) & 1;
    int wr   = (idx >> 8) & 1;
    int kt   = (idx >> 9) & 31;
    int p    = idx >> 14;
    int h = p * 128 + wr * 64 + (mp * 2 + halfsel) * 16 + (lane & 15);
    int k = kt * 32 + (lane >> 4) * 8;
    const float* src = W1 + (size_t)h * D_SZ + k;
    float4 v0 = *reinterpret_cast<const float4*>(src);
    float4 v1 = *reinterpret_cast<const float4*>(src + 4);
    float f[8] = {v0.x, v0.y, v0.z, v0.w, v1.x, v1.y, v1.z, v1.w};
    union { unsigned char b[8]; uint2 u; } q;
    #pragma unroll
    for (int j = 0; j < 8; ++j) q.b[j] = to_fp8(32.0f * f[j]);
    size_t off = (size_t)p * 131072 + (size_t)kt * 4096 + wr * 2048 + mp * 1024
               + lane * 16 + halfsel * 8;
    *reinterpret_cast<uint2*>(w1f + off) = q.u;
}

// ---------------- x -> fp8 frags: [bg(256)][kt(32)][np(2)][lane(64)][16B] ------------
__global__ void k_xfrag8(const float* __restrict__ x, unsigned char* __restrict__ xf) {
    int idx = blockIdx.x * blockDim.x + threadIdx.x;   // 0..2097151
    int halfsel = idx & 1;
    int lane = (idx >> 1) & 63;
    int np   = (idx >> 7) & 1;
    int kt   = (idx >> 8) & 31;
    int bg   = idx >> 13;
    int b = bg * 64 + (np * 2 + halfsel) * 16 + (lane & 15);
    int k = kt * 32 + (lane >> 4) * 8;
    const float* src = x + (size_t)b * D_SZ + k;
    float4 v0 = *reinterpret_cast<const float4*>(src);
    float4 v1 = *reinterpret_cast<const float4*>(src + 4);
    float f[8] = {v0.x, v0.y, v0.z, v0.w, v1.x, v1.y, v1.z, v1.w};
    union { unsigned char b[8]; uint2 u; } q;
    #pragma unroll
    for (int j = 0; j < 8; ++j) q.b[j] = to_fp8(f[j]);
    size_t off = (size_t)bg * 65536 + (size_t)kt * 2048 + np * 1024
               + lane * 16 + halfsel * 8;
    *reinterpret_cast<uint2*>(xf + off) = q.u;
}

// ---------------- W2 -> fp8 frags: [kt(64)][ntp(4)][lane(64)][16B], k-perm baked -----
// 16384 threads EXACTLY.
__global__ void k_w2frag8(const float* __restrict__ W2, unsigned char* __restrict__ w2f) {
    const int perm[8] = {0, 2, 1, 3, 4, 6, 5, 7};
    int idx = blockIdx.x * blockDim.x + threadIdx.x;   // 0..16383
    int lane = idx & 63;
    int ntp  = (idx >> 6) & 3;
    int kt   = idx >> 8;                               // 0..63
    union { unsigned char b[16]; uint4 u; } q;
    #pragma unroll
    for (int half = 0; half < 2; ++half) {
        int c = (ntp * 2 + half) * 16 + (lane & 15);
        const float* src = W2 + (size_t)c * H_SZ + kt * 32 + (lane >> 4) * 8;
        float4 v0 = *reinterpret_cast<const float4*>(src);
        float4 v1 = *reinterpret_cast<const float4*>(src + 4);
        float f[8] = {v0.x, v0.y, v0.z, v0.w, v1.x, v1.y, v1.z, v1.w};
        #pragma unroll
        for (int j = 0; j < 8; ++j)
            q.b[half * 8 + j] = to_fp8(32.0f * f[perm[j]]);
    }
    *reinterpret_cast<uint4*>(w2f + (size_t)idx * 16) = q.u;
}

// ---------------- K1: LDS-free fp8 frag-GEMM + closed-form LIF -----------------------
// Hard reset => spike train is exactly periodic with period p(i1):
//   p = ceil(log2(1 - 0.1/i1) / log2(0.9)), spikes at t = p-1, 2p-1, ...
// 22-entry LDS LUT holds the 20-bit mask per period; p>=21 or i1<th20 -> 0.
// Masks written in K2's fragment order [bt(1024)][kt(64)][lane(64)][8] -> fully
// coalesced stores (round-12: 4KB-strided 8B stores cost ~2x write amplification).
__global__ __launch_bounds__(256, 2) void k_gemm1_fp8(
    const unsigned char* __restrict__ xf,
    const unsigned char* __restrict__ w1f,
    const float* __restrict__ b1,
    unsigned short* __restrict__ M16,
    unsigned char* __restrict__ M4,
    unsigned int* __restrict__ spike_count)
{
    __shared__ unsigned lutm[22];
    const int tid  = threadIdx.x;
    if (tid < 22) {
        unsigned m = 0;
        if (tid >= 1 && tid <= 20)
            for (int t = tid - 1; t < T_STEPS; t += tid) m |= 1u << t;
        lutm[tid] = m;
    }
    __syncthreads();

    const int wv   = tid >> 6;
    const int lane = tid & 63;
    const int l15  = lane & 15;
    const int g    = lane >> 4;
    const int wr   = wv >> 1;
    const int wc   = wv & 1;

    const int wg    = blockIdx.x;
    const int xcd   = wg & 7;
    const int local = wg >> 3;
    const int sc    = local >> 4;
    const int sl    = local & 15;
    const int b_panel = wg < 0 ? 0 : (xcd * 16 + (sc >> 2) * 4 + (sl >> 2));
    const int h_idx   = (sc & 3) * 4 + (sl & 3);

    f32x4 acc[4][4];
    #pragma unroll
    for (int i = 0; i < 4; ++i)
        #pragma unroll
        for (int j = 0; j < 4; ++j)
            acc[i][j] = (f32x4){0.f, 0.f, 0.f, 0.f};

    const unsigned char* Ap = w1f + (size_t)h_idx * 131072 + wr * 2048 + lane * 16;
    const unsigned char* Bp = xf + (size_t)(b_panel * 2 + wc) * 65536 + lane * 16;

    #pragma unroll 2
    for (int kt = 0; kt < 32; ++kt) {
        uint4 a0 = *reinterpret_cast<const uint4*>(Ap);
        uint4 a1 = *reinterpret_cast<const uint4*>(Ap + 1024);
        uint4 c0 = *reinterpret_cast<const uint4*>(Bp);
        uint4 c1 = *reinterpret_cast<const uint4*>(Bp + 1024);
        long A[4], Bq[4];
        A[0] = pk64(a0.x, a0.y); A[1] = pk64(a0.z, a0.w);
        A[2] = pk64(a1.x, a1.y); A[3] = pk64(a1.z, a1.w);
        Bq[0] = pk64(c0.x, c0.y); Bq[1] = pk64(c0.z, c0.w);
        Bq[2] = pk64(c1.x, c1.y); Bq[3] = pk64(c1.z, c1.w);
        #pragma unroll
        for (int m = 0; m < 4; ++m)
            #pragma unroll
            for (int n = 0; n < 4; ++n)
                acc[m][n] = __builtin_amdgcn_mfma_f32_16x16x32_fp8_fp8(
                    A[m], Bq[n], acc[m][n], 0, 0, 0);
        Ap += 4096;
        Bp += 2048;
    }

    int spikes = 0;
    #pragma unroll
    for (int m = 0; m < 4; ++m) {
        const int h0l = h_idx * 128 + wr * 64 + m * 16 + g * 4;
        const int ktm = h_idx * 4 + wr * 2 + (m >> 1);
        const int g2  = (m & 1) * 2 + (g >> 1);
        float4 bias = *reinterpret_cast<const float4*>(b1 + h0l);
        float bj[4] = {bias.x, bias.y, bias.z, bias.w};
        #pragma unroll
        for (int n = 0; n < 4; ++n) {
            const int bt = b_panel * 8 + wc * 4 + n;
            unsigned mk[4];
            #pragma unroll
            for (int j = 0; j < 4; ++j) {
                float i1 = __fmul_rn(acc[m][n][j], 0.03125f) + bj[j];
                float arg = fmaf(-0.1f, __builtin_amdgcn_rcpf(i1), 1.0f);
                float pf = ceilf(__log2f(arg) * -6.578813478960192f);
                int p = (int)pf;
                p = p < 1 ? 1 : (p > 21 ? 21 : p);
                unsigned mask = lutm[p];
                mk[j] = (i1 >= 0.113843485f) ? mask : 0u;
                spikes += __popc(mk[j]);
            }
            const size_t slot = ((size_t)bt * 64 + ktm) * 64 + g2 * 16 + l15;
            *reinterpret_cast<uint2*>(M16 + slot * 8 + (g & 1) * 4) =
                make_uint2((mk[0] & 0xffffu) | (mk[1] << 16),
                           (mk[2] & 0xffffu) | (mk[3] << 16));
            *reinterpret_cast<unsigned int*>(M4 + slot * 8 + (g & 1) * 4) =
                (mk[0] >> 16) | ((mk[1] >> 16) << 8) | ((mk[2] >> 16) << 16) | ((mk[3] >> 16) << 24);
        }
    }
    #pragma unroll
    for (int off = 32; off > 0; off >>= 1)
        spikes += __shfl_down(spikes, off);
    if (lane == 0)
        atomicAdd(spike_count, (unsigned int)spikes);
}

// ---------------- K2: layer 2 fp8, LDS-free main loop, 4 waves x 8 nt ----------------
// Masks now read from fragment order: per kt one contiguous 1KB wave-load.
__global__ __launch_bounds__(256, 2) void k_layer2_fp8(
    const unsigned short* __restrict__ M16,
    const unsigned char* __restrict__ M4,
    const unsigned char* __restrict__ W2f,
    const float* __restrict__ b2,
    float* __restrict__ out)
{
    __shared__ __align__(16) float smem[5700];   // 16b x 16c (pad 17) x 21t
    const int tid  = threadIdx.x;
    const int tg   = tid >> 6;        // wave = t-group: t in [tg*5, tg*5+5)
    const int lane = tid & 63;
    const int l15  = lane & 15;
    const int g    = lane >> 4;
    const int b0   = blockIdx.x * 16;
    const int t0   = tg * 5;

    f32x4 acc[8][5];
    #pragma unroll
    for (int n = 0; n < 8; ++n)
        #pragma unroll
        for (int t = 0; t < 5; ++t)
            acc[n][t] = (f32x4){0.f, 0.f, 0.f, 0.f};

    // frag-ordered mask bases: entry = [bt][kt][lane][8]
    const unsigned short* m16p = M16 + ((size_t)blockIdx.x * 4096 + lane * 8);
    const unsigned char*  m4p  = M4  + ((size_t)blockIdx.x * 4096 + lane * 8) ;
    const unsigned char*  fbase  = W2f + (size_t)lane * 16;

    for (int kt = 0; kt < 64; ++kt) {
        uint4 w16 = *reinterpret_cast<const uint4*>(m16p + (size_t)kt * 512);
        uint2 w4 = make_uint2(0u, 0u);
        if (tg == 3)
            w4 = *reinterpret_cast<const uint2*>(m4p + (size_t)kt * 512);

        long A[5];
        #pragma unroll
        for (int tl = 0; tl < 5; ++tl) {
            const int t = t0 + tl;
            unsigned dw0, dw1;
            if (t < 16) {
                dw0 = ((w16.x >> t) & 0x10001u) * 0x38u | ((w16.y >> t) & 0x10001u) * 0x3800u;
                dw1 = ((w16.z >> t) & 0x10001u) * 0x38u | ((w16.w >> t) & 0x10001u) * 0x3800u;
            } else {
                const int tt = t - 16;
                unsigned f0 = ((w4.x >> tt) & 0x01010101u) * 0x38u;
                unsigned f1 = ((w4.y >> tt) & 0x01010101u) * 0x38u;
                dw0 = __builtin_amdgcn_perm(0u, f0, 0x03010200u);   // bytes [0,2,1,3]
                dw1 = __builtin_amdgcn_perm(0u, f1, 0x03010200u);
            }
            A[tl] = pk64(dw0, dw1);
        }

        const unsigned char* fk = fbase + (size_t)kt * 4096;
        long Bf[8];
        #pragma unroll
        for (int ntp = 0; ntp < 4; ++ntp) {
            uint4 v = *reinterpret_cast<const uint4*>(fk + ntp * 1024);
            Bf[ntp * 2]     = pk64(v.x, v.y);
            Bf[ntp * 2 + 1] = pk64(v.z, v.w);
        }
        #pragma unroll
        for (int tl = 0; tl < 5; ++tl)
            #pragma unroll
            for (int nt = 0; nt < 8; ++nt)
                acc[nt][tl] = __builtin_amdgcn_mfma_f32_16x16x32_fp8_fp8(
                    A[tl], Bf[nt], acc[nt][tl], 0, 0, 0);
    }

    // epilogue: 8 chunks of 16 cols; transpose through LDS, then LIF per (b,c)
    #pragma unroll
    for (int q = 0; q < 8; ++q) {
        __syncthreads();
        #pragma unroll
        for (int tl = 0; tl < 5; ++tl)
            #pragma unroll
            for (int j = 0; j < 4; ++j)
                smem[((g * 4 + j) * 17 + l15) * 21 + (t0 + tl)] = acc[q][tl][j];
        __syncthreads();
        {
            const int bl  = tid >> 4;     // 0..15
            const int c16 = tid & 15;
            const int c   = q * 16 + c16;
            const float bias = b2[c];
            float u2 = 0.0f; int cnt = 0;
            #pragma unroll
            for (int t = 0; t < T_STEPS; ++t) {
                float X = __fadd_rn(__fmul_rn(smem[(bl * 17 + c16) * 21 + t], 0.03125f), bias);
                u2 = __fadd_rn(__fmul_rn(0.9f, u2), X);
                if (u2 >= 1.0f) { cnt++; u2 = 0.0f; }
            }
            out[(size_t)(b0 + bl) * C_SZ + c] = (float)cnt / 20.0f;
        }
    }
}

// ---------------- K3: mean_spikes = total / (B * T) ----------------
__global__ void k_finalize(const unsigned int* __restrict__ spike_count, float* __restrict__ out) {
    out[(size_t)B_SZ * C_SZ] = (float)(*spike_count) / (float)((size_t)B_SZ * T_STEPS);
}

extern "C" void kernel_launch(void* const* d_in, const int* in_sizes, int n_in,
                              void* d_out, int out_size, void* d_ws, size_t ws_size,
                              hipStream_t stream) {
    const float* x  = (const float*)d_in[0];
    const float* W1 = (const float*)d_in[1];
    const float* b1 = (const float*)d_in[2];
    const float* W2 = (const float*)d_in[3];
    const float* b2 = (const float*)d_in[4];
    float* out = (float*)d_out;

    char* ws = (char*)d_ws;
    const size_t m16_b  = (size_t)B_SZ * H_SZ * 2;   // 67.1 MB
    const size_t m4_b   = (size_t)B_SZ * H_SZ;       // 33.6 MB
    const size_t xf8_b  = (size_t)B_SZ * D_SZ;       // 16.8 MB
    const size_t w1f8_b = (size_t)H_SZ * D_SZ;       //  2.1 MB
    const size_t w2f8_b = (size_t)C_SZ * H_SZ;       //  0.26 MB

    size_t off = 0;
    unsigned short* M16  = (unsigned short*)(ws + off); off += m16_b;
    unsigned char*  M4   = (unsigned char*)(ws + off);  off += m4_b;
    unsigned char*  xf8  = (unsigned char*)(ws + off);  off += xf8_b;
    unsigned char*  w1f8 = (unsigned char*)(ws + off);  off += w1f8_b;
    unsigned char*  w2f8 = (unsigned char*)(ws + off);  off += w2f8_b;
    unsigned int* counter = (unsigned int*)(ws + off);  off += 256;

    hipMemsetAsync(counter, 0, sizeof(unsigned int), stream);

    k_w1frag8<<<1024, 256, 0, stream>>>(W1, w1f8);
    k_w2frag8<<<64, 256, 0, stream>>>(W2, w2f8);     // 16384 threads EXACT
    k_xfrag8<<<8192, 256, 0, stream>>>(x, xf8);

    k_gemm1_fp8<<<2048, 256, 0, stream>>>(xf8, w1f8, b1, M16, M4, counter);

    k_layer2_fp8<<<B_SZ / 16, 256, 0, stream>>>(M16, M4, w2f8, b2, out);

    k_finalize<<<1, 1, 0, stream>>>(counter, out);
}

// Round 14
// 237.795 us; speedup vs baseline: 2.3879x; 1.2052x over previous
//
#include <hip/hip_runtime.h>
#include <hip/hip_fp8.h>

#define B_SZ 16384
#define D_SZ 1024
#define H_SZ 2048
#define C_SZ 128
#define T_STEPS 20

typedef __attribute__((ext_vector_type(4))) float f32x4;
typedef __attribute__((ext_vector_type(4))) int   i32x4;

__device__ __forceinline__ unsigned char to_fp8(float f) {
    __hip_fp8_e4m3 q(f);
    return (unsigned char)q.__x;
}

__device__ __forceinline__ long pk64(unsigned int lo, unsigned int hi) {
    return (long)(((unsigned long long)hi << 32) | (unsigned long long)lo);
}

// ---------------- W1 -> fp8 frags: [p(16)][kt(32)][wr(2)][mp(2)][lane(64)][16B] ------
__global__ void k_w1frag8(const float* __restrict__ W1, unsigned char* __restrict__ w1f) {
    int idx = blockIdx.x * blockDim.x + threadIdx.x;   // 0..262143
    int halfsel = idx & 1;
    int lane = (idx >> 1) & 63;
    int mp   = (idx >> 7) & 1;
    int wr   = (idx >> 8) & 1;
    int kt   = (idx >> 9) & 31;
    int p    = idx >> 14;
    int h = p * 128 + wr * 64 + (mp * 2 + halfsel) * 16 + (lane & 15);
    int k = kt * 32 + (lane >> 4) * 8;
    const float* src = W1 + (size_t)h * D_SZ + k;
    float4 v0 = *reinterpret_cast<const float4*>(src);
    float4 v1 = *reinterpret_cast<const float4*>(src + 4);
    float f[8] = {v0.x, v0.y, v0.z, v0.w, v1.x, v1.y, v1.z, v1.w};
    union { unsigned char b[8]; uint2 u; } q;
    #pragma unroll
    for (int j = 0; j < 8; ++j) q.b[j] = to_fp8(32.0f * f[j]);
    size_t off = (size_t)p * 131072 + (size_t)kt * 4096 + wr * 2048 + mp * 1024
               + lane * 16 + halfsel * 8;
    *reinterpret_cast<uint2*>(w1f + off) = q.u;
}

// ---------------- x -> fp8 frags: [bg(256)][kt(32)][np(2)][lane(64)][16B] ------------
__global__ void k_xfrag8(const float* __restrict__ x, unsigned char* __restrict__ xf) {
    int idx = blockIdx.x * blockDim.x + threadIdx.x;   // 0..2097151
    int halfsel = idx & 1;
    int lane = (idx >> 1) & 63;
    int np   = (idx >> 7) & 1;
    int kt   = (idx >> 8) & 31;
    int bg   = idx >> 13;
    int b = bg * 64 + (np * 2 + halfsel) * 16 + (lane & 15);
    int k = kt * 32 + (lane >> 4) * 8;
    const float* src = x + (size_t)b * D_SZ + k;
    float4 v0 = *reinterpret_cast<const float4*>(src);
    float4 v1 = *reinterpret_cast<const float4*>(src + 4);
    float f[8] = {v0.x, v0.y, v0.z, v0.w, v1.x, v1.y, v1.z, v1.w};
    union { unsigned char b[8]; uint2 u; } q;
    #pragma unroll
    for (int j = 0; j < 8; ++j) q.b[j] = to_fp8(f[j]);
    size_t off = (size_t)bg * 65536 + (size_t)kt * 2048 + np * 1024
               + lane * 16 + halfsel * 8;
    *reinterpret_cast<uint2*>(xf + off) = q.u;
}

// ---------------- W2 -> i8 frags: [kt64(32)][nt(8)][lane(64)][16B], k-perm baked -----
// byte j: c = nt*16+(lane&15); k = kt64*64 + (lane>>4)*16 + (j&~3) + {0,2,1,3}[j&3];
// value = clamp(rint(1024 * W2[c][k]), -127, 127).  16384 threads EXACTLY.
__global__ void k_w2fragi8(const float* __restrict__ W2, signed char* __restrict__ w2q) {
    const int perm4[4] = {0, 2, 1, 3};
    int idx = blockIdx.x * blockDim.x + threadIdx.x;   // 0..16383
    int lane = idx & 63;
    int nt   = (idx >> 6) & 7;
    int kt   = idx >> 9;                               // 0..31
    int c = nt * 16 + (lane & 15);
    int hbase = kt * 64 + (lane >> 4) * 16;
    const float* src = W2 + (size_t)c * H_SZ + hbase;
    float f[16];
    #pragma unroll
    for (int q4 = 0; q4 < 4; ++q4) {
        float4 v = *reinterpret_cast<const float4*>(src + q4 * 4);
        f[q4 * 4 + 0] = v.x; f[q4 * 4 + 1] = v.y; f[q4 * 4 + 2] = v.z; f[q4 * 4 + 3] = v.w;
    }
    union { signed char b[16]; uint4 u; } q;
    #pragma unroll
    for (int j = 0; j < 16; ++j) {
        int k = (j & ~3) + perm4[j & 3];
        float v = rintf(1024.0f * f[k]);
        v = v > 127.0f ? 127.0f : (v < -127.0f ? -127.0f : v);
        q.b[j] = (signed char)(int)v;
    }
    *reinterpret_cast<uint4*>(w2q + (size_t)idx * 16) = q.u;
}

// ---------------- K1: LDS-free fp8 frag-GEMM + closed-form LIF -----------------------
// Masks written in K2's K=64 fragment order: record = [bt(1024)][kt64(32)][lane(64)],
// 16 u16 (M16) + 16 u8 (M4) per record; K1 wave covers each 512B/256B segment fully.
__global__ __launch_bounds__(256, 2) void k_gemm1_fp8(
    const unsigned char* __restrict__ xf,
    const unsigned char* __restrict__ w1f,
    const float* __restrict__ b1,
    unsigned short* __restrict__ M16,
    unsigned char* __restrict__ M4,
    unsigned int* __restrict__ spike_count)
{
    __shared__ unsigned lutm[22];
    const int tid  = threadIdx.x;
    if (tid < 22) {
        unsigned m = 0;
        if (tid >= 1 && tid <= 20)
            for (int t = tid - 1; t < T_STEPS; t += tid) m |= 1u << t;
        lutm[tid] = m;
    }
    __syncthreads();

    const int wv   = tid >> 6;
    const int lane = tid & 63;
    const int l15  = lane & 15;
    const int g    = lane >> 4;
    const int wr   = wv >> 1;
    const int wc   = wv & 1;

    const int wg    = blockIdx.x;
    const int xcd   = wg & 7;
    const int local = wg >> 3;
    const int sc    = local >> 4;
    const int sl    = local & 15;
    const int b_panel = xcd * 16 + (sc >> 2) * 4 + (sl >> 2);
    const int h_idx   = (sc & 3) * 4 + (sl & 3);

    f32x4 acc[4][4];
    #pragma unroll
    for (int i = 0; i < 4; ++i)
        #pragma unroll
        for (int j = 0; j < 4; ++j)
            acc[i][j] = (f32x4){0.f, 0.f, 0.f, 0.f};

    const unsigned char* Ap = w1f + (size_t)h_idx * 131072 + wr * 2048 + lane * 16;
    const unsigned char* Bp = xf + (size_t)(b_panel * 2 + wc) * 65536 + lane * 16;

    #pragma unroll 2
    for (int kt = 0; kt < 32; ++kt) {
        uint4 a0 = *reinterpret_cast<const uint4*>(Ap);
        uint4 a1 = *reinterpret_cast<const uint4*>(Ap + 1024);
        uint4 c0 = *reinterpret_cast<const uint4*>(Bp);
        uint4 c1 = *reinterpret_cast<const uint4*>(Bp + 1024);
        long A[4], Bq[4];
        A[0] = pk64(a0.x, a0.y); A[1] = pk64(a0.z, a0.w);
        A[2] = pk64(a1.x, a1.y); A[3] = pk64(a1.z, a1.w);
        Bq[0] = pk64(c0.x, c0.y); Bq[1] = pk64(c0.z, c0.w);
        Bq[2] = pk64(c1.x, c1.y); Bq[3] = pk64(c1.z, c1.w);
        #pragma unroll
        for (int m = 0; m < 4; ++m)
            #pragma unroll
            for (int n = 0; n < 4; ++n)
                acc[m][n] = __builtin_amdgcn_mfma_f32_16x16x32_fp8_fp8(
                    A[m], Bq[n], acc[m][n], 0, 0, 0);
        Ap += 4096;
        Bp += 2048;
    }

    int spikes = 0;
    #pragma unroll
    for (int m = 0; m < 4; ++m) {
        const int h0l = h_idx * 128 + wr * 64 + m * 16 + g * 4;
        const int kt64 = h_idx * 2 + wr;
        const int k2lane = m * 16 + l15;
        float4 bias = *reinterpret_cast<const float4*>(b1 + h0l);
        float bj[4] = {bias.x, bias.y, bias.z, bias.w};
        #pragma unroll
        for (int n = 0; n < 4; ++n) {
            const int bt = b_panel * 8 + wc * 4 + n;
            unsigned mk[4];
            #pragma unroll
            for (int j = 0; j < 4; ++j) {
                float i1 = __fmul_rn(acc[m][n][j], 0.03125f) + bj[j];
                float arg = fmaf(-0.1f, __builtin_amdgcn_rcpf(i1), 1.0f);
                float pf = ceilf(__log2f(arg) * -6.578813478960192f);
                int p = (int)pf;
                p = p < 1 ? 1 : (p > 21 ? 21 : p);
                unsigned mask = lutm[p];
                mk[j] = (i1 >= 0.113843485f) ? mask : 0u;
                spikes += __popc(mk[j]);
            }
            const size_t rec = ((size_t)bt * 32 + kt64) * 64 + k2lane;
            *reinterpret_cast<uint2*>(M16 + rec * 16 + g * 4) =
                make_uint2((mk[0] & 0xffffu) | (mk[1] << 16),
                           (mk[2] & 0xffffu) | (mk[3] << 16));
            *reinterpret_cast<unsigned int*>(M4 + rec * 16 + g * 4) =
                (mk[0] >> 16) | ((mk[1] >> 16) << 8) | ((mk[2] >> 16) << 16) | ((mk[3] >> 16) << 24);
        }
    }
    #pragma unroll
    for (int off = 32; off > 0; off >>= 1)
        spikes += __shfl_down(spikes, off);
    if (lane == 0)
        atomicAdd(spike_count, (unsigned int)spikes);
}

// ---------------- K2: layer 2 via i8 MFMA K=64, LDS-free main loop -------------------
// 4 waves; wave tg owns 5 timesteps x 128 cols, 16 b-rows/block. Per kt64: 3 mask
// loads + 8 B loads + 5 A-expands (bits -> 0x01 bytes) + 40 mfma_i32_16x16x64_i8.
// A and B share the per-4 byte-perm {0,2,1,3}; i32 accumulate exact; inj = acc/1024.
__global__ __launch_bounds__(256, 2) void k_layer2_i8(
    const unsigned short* __restrict__ M16,
    const unsigned char* __restrict__ M4,
    const signed char* __restrict__ W2q,
    const float* __restrict__ b2,
    float* __restrict__ out)
{
    __shared__ __align__(16) float smem[5700];   // 16b x 16c (pad 17) x 21t
    const int tid  = threadIdx.x;
    const int tg   = tid >> 6;        // wave = t-group: t in [tg*5, tg*5+5)
    const int lane = tid & 63;
    const int l15  = lane & 15;
    const int g    = lane >> 4;
    const int b0   = blockIdx.x * 16;
    const int t0   = tg * 5;

    i32x4 acc[8][5];
    #pragma unroll
    for (int n = 0; n < 8; ++n)
        #pragma unroll
        for (int t = 0; t < 5; ++t)
            acc[n][t] = (i32x4){0, 0, 0, 0};

    const unsigned short* m16p = M16 + (size_t)blockIdx.x * 32768 + lane * 16;
    const unsigned char*  m4p  = M4  + (size_t)blockIdx.x * 32768 + lane * 16;
    const signed char*    fbase = W2q + (size_t)lane * 16;

    for (int kt = 0; kt < 32; ++kt) {
        const unsigned short* mp = m16p + (size_t)kt * 1024;
        uint4 wa = *reinterpret_cast<const uint4*>(mp);
        uint4 wb = *reinterpret_cast<const uint4*>(mp + 8);
        uint4 w4 = make_uint4(0u, 0u, 0u, 0u);
        if (tg == 3)
            w4 = *reinterpret_cast<const uint4*>(m4p + (size_t)kt * 1024);

        union { i32x4 v; unsigned u[4]; } A[5];
        #pragma unroll
        for (int tl = 0; tl < 5; ++tl) {
            const int t = t0 + tl;
            if (t < 16) {
                A[tl].u[0] = ((wa.x >> t) & 0x10001u) | (((wa.y >> t) & 0x10001u) << 8);
                A[tl].u[1] = ((wa.z >> t) & 0x10001u) | (((wa.w >> t) & 0x10001u) << 8);
                A[tl].u[2] = ((wb.x >> t) & 0x10001u) | (((wb.y >> t) & 0x10001u) << 8);
                A[tl].u[3] = ((wb.z >> t) & 0x10001u) | (((wb.w >> t) & 0x10001u) << 8);
            } else {
                const int tt = t - 16;
                A[tl].u[0] = __builtin_amdgcn_perm(0u, (w4.x >> tt) & 0x01010101u, 0x03010200u);
                A[tl].u[1] = __builtin_amdgcn_perm(0u, (w4.y >> tt) & 0x01010101u, 0x03010200u);
                A[tl].u[2] = __builtin_amdgcn_perm(0u, (w4.z >> tt) & 0x01010101u, 0x03010200u);
                A[tl].u[3] = __builtin_amdgcn_perm(0u, (w4.w >> tt) & 0x01010101u, 0x03010200u);
            }
        }

        const signed char* fk = fbase + (size_t)kt * 8192;
        i32x4 Bv[8];
        #pragma unroll
        for (int nt = 0; nt < 8; ++nt)
            Bv[nt] = *reinterpret_cast<const i32x4*>(fk + nt * 1024);
        #pragma unroll
        for (int tl = 0; tl < 5; ++tl)
            #pragma unroll
            for (int nt = 0; nt < 8; ++nt)
                acc[nt][tl] = __builtin_amdgcn_mfma_i32_16x16x64_i8(
                    A[tl].v, Bv[nt], acc[nt][tl], 0, 0, 0);
    }

    // epilogue: 8 chunks of 16 cols; transpose through LDS, then LIF per (b,c)
    #pragma unroll
    for (int q = 0; q < 8; ++q) {
        __syncthreads();
        #pragma unroll
        for (int tl = 0; tl < 5; ++tl)
            #pragma unroll
            for (int j = 0; j < 4; ++j)
                smem[((g * 4 + j) * 17 + l15) * 21 + (t0 + tl)] = (float)acc[q][tl][j];
        __syncthreads();
        {
            const int bl  = tid >> 4;     // 0..15
            const int c16 = tid & 15;
            const int c   = q * 16 + c16;
            const float bias = b2[c];
            float u2 = 0.0f; int cnt = 0;
            #pragma unroll
            for (int t = 0; t < T_STEPS; ++t) {
                float X = __fadd_rn(__fmul_rn(smem[(bl * 17 + c16) * 21 + t], 0.0009765625f), bias);
                u2 = __fadd_rn(__fmul_rn(0.9f, u2), X);
                if (u2 >= 1.0f) { cnt++; u2 = 0.0f; }
            }
            out[(size_t)(b0 + bl) * C_SZ + c] = (float)cnt / 20.0f;
        }
    }
}

// ---------------- K3: mean_spikes = total / (B * T) ----------------
__global__ void k_finalize(const unsigned int* __restrict__ spike_count, float* __restrict__ out) {
    out[(size_t)B_SZ * C_SZ] = (float)(*spike_count) / (float)((size_t)B_SZ * T_STEPS);
}

extern "C" void kernel_launch(void* const* d_in, const int* in_sizes, int n_in,
                              void* d_out, int out_size, void* d_ws, size_t ws_size,
                              hipStream_t stream) {
    const float* x  = (const float*)d_in[0];
    const float* W1 = (const float*)d_in[1];
    const float* b1 = (const float*)d_in[2];
    const float* W2 = (const float*)d_in[3];
    const float* b2 = (const float*)d_in[4];
    float* out = (float*)d_out;

    char* ws = (char*)d_ws;
    const size_t m16_b  = (size_t)B_SZ * H_SZ * 2;   // 67.1 MB
    const size_t m4_b   = (size_t)B_SZ * H_SZ;       // 33.6 MB
    const size_t xf8_b  = (size_t)B_SZ * D_SZ;       // 16.8 MB
    const size_t w1f8_b = (size_t)H_SZ * D_SZ;       //  2.1 MB
    const size_t w2q_b  = (size_t)C_SZ * H_SZ;       //  0.26 MB

    size_t off = 0;
    unsigned short* M16  = (unsigned short*)(ws + off); off += m16_b;
    unsigned char*  M4   = (unsigned char*)(ws + off);  off += m4_b;
    unsigned char*  xf8  = (unsigned char*)(ws + off);  off += xf8_b;
    unsigned char*  w1f8 = (unsigned char*)(ws + off);  off += w1f8_b;
    signed char*    w2q  = (signed char*)(ws + off);    off += w2q_b;
    unsigned int* counter = (unsigned int*)(ws + off);  off += 256;

    hipMemsetAsync(counter, 0, sizeof(unsigned int), stream);

    k_w1frag8<<<1024, 256, 0, stream>>>(W1, w1f8);
    k_w2fragi8<<<64, 256, 0, stream>>>(W2, w2q);     // 16384 threads EXACT
    k_xfrag8<<<8192, 256, 0, stream>>>(x, xf8);

    k_gemm1_fp8<<<2048, 256, 0, stream>>>(xf8, w1f8, b1, M16, M4, counter);

    k_layer2_i8<<<B_SZ / 16, 256, 0, stream>>>(M16, M4, w2q, b2, out);

    k_finalize<<<1, 1, 0, stream>>>(counter, out);
}

// Round 15
// 234.591 us; speedup vs baseline: 2.4206x; 1.0137x over previous
//
#include <hip/hip_runtime.h>

#define B_SZ 16384
#define D_SZ 1024
#define H_SZ 2048
#define C_SZ 128
#define T_STEPS 20

typedef __attribute__((ext_vector_type(4))) float f32x4;
typedef __attribute__((ext_vector_type(4))) int   i32x4;

__device__ __forceinline__ signed char to_i8(float f, float s) {
    float v = rintf(s * f);
    v = v > 127.0f ? 127.0f : (v < -127.0f ? -127.0f : v);
    return (signed char)(int)v;
}

// ---------------- W1 -> i8 frags: [p(16)][kt(16)][wr(2)][m(4)][lane(64)][16B] --------
// byte j: h = p*128 + wr*64 + m*16 + (lane&15); k = kt*64 + (lane>>4)*16 + j.
// value = clamp(rint(1024 * W1[h][k])). 131072 threads exactly.
__global__ void k_w1fragi8(const float* __restrict__ W1, signed char* __restrict__ w1f) {
    int idx = blockIdx.x * blockDim.x + threadIdx.x;   // 0..131071
    int lane = idx & 63;
    int m    = (idx >> 6) & 3;
    int wr   = (idx >> 8) & 1;
    int kt   = (idx >> 9) & 15;
    int p    = idx >> 13;
    int h = p * 128 + wr * 64 + m * 16 + (lane & 15);
    int k = kt * 64 + (lane >> 4) * 16;
    const float* src = W1 + (size_t)h * D_SZ + k;
    union { signed char b[16]; uint4 u; } q;
    #pragma unroll
    for (int q4 = 0; q4 < 4; ++q4) {
        float4 v = *reinterpret_cast<const float4*>(src + q4 * 4);
        q.b[q4 * 4 + 0] = to_i8(v.x, 1024.0f);
        q.b[q4 * 4 + 1] = to_i8(v.y, 1024.0f);
        q.b[q4 * 4 + 2] = to_i8(v.z, 1024.0f);
        q.b[q4 * 4 + 3] = to_i8(v.w, 1024.0f);
    }
    size_t off = (size_t)p * 131072 + (size_t)kt * 8192 + wr * 4096 + m * 1024 + lane * 16;
    *reinterpret_cast<uint4*>(w1f + off) = q.u;
}

// ---------------- x -> i8 frags: [bp(128)][kt(16)][wc(2)][n(4)][lane(64)][16B] -------
// byte j: b = bp*128 + wc*64 + n*16 + (lane&15); k = kt*64 + (lane>>4)*16 + j.
// value = clamp(rint(32 * x[b][k])). 1048576 threads exactly.
__global__ void k_xfragi8(const float* __restrict__ x, signed char* __restrict__ xf) {
    int idx = blockIdx.x * blockDim.x + threadIdx.x;   // 0..1048575
    int lane = idx & 63;
    int n    = (idx >> 6) & 3;
    int wc   = (idx >> 8) & 1;
    int kt   = (idx >> 9) & 15;
    int bp   = idx >> 13;
    int b = bp * 128 + wc * 64 + n * 16 + (lane & 15);
    int k = kt * 64 + (lane >> 4) * 16;
    const float* src = x + (size_t)b * D_SZ + k;
    union { signed char b[16]; uint4 u; } q;
    #pragma unroll
    for (int q4 = 0; q4 < 4; ++q4) {
        float4 v = *reinterpret_cast<const float4*>(src + q4 * 4);
        q.b[q4 * 4 + 0] = to_i8(v.x, 32.0f);
        q.b[q4 * 4 + 1] = to_i8(v.y, 32.0f);
        q.b[q4 * 4 + 2] = to_i8(v.z, 32.0f);
        q.b[q4 * 4 + 3] = to_i8(v.w, 32.0f);
    }
    size_t off = (size_t)bp * 131072 + (size_t)kt * 8192 + wc * 4096 + n * 1024 + lane * 16;
    *reinterpret_cast<uint4*>(xf + off) = q.u;
}

// ---------------- W2 -> i8 frags: [kt64(32)][nt(8)][lane(64)][16B], k-perm baked -----
// 16384 threads EXACTLY.
__global__ void k_w2fragi8(const float* __restrict__ W2, signed char* __restrict__ w2q) {
    const int perm4[4] = {0, 2, 1, 3};
    int idx = blockIdx.x * blockDim.x + threadIdx.x;   // 0..16383
    int lane = idx & 63;
    int nt   = (idx >> 6) & 7;
    int kt   = idx >> 9;                               // 0..31
    int c = nt * 16 + (lane & 15);
    int hbase = kt * 64 + (lane >> 4) * 16;
    const float* src = W2 + (size_t)c * H_SZ + hbase;
    float f[16];
    #pragma unroll
    for (int q4 = 0; q4 < 4; ++q4) {
        float4 v = *reinterpret_cast<const float4*>(src + q4 * 4);
        f[q4 * 4 + 0] = v.x; f[q4 * 4 + 1] = v.y; f[q4 * 4 + 2] = v.z; f[q4 * 4 + 3] = v.w;
    }
    union { signed char b[16]; uint4 u; } q;
    #pragma unroll
    for (int j = 0; j < 16; ++j) {
        int k = (j & ~3) + perm4[j & 3];
        q.b[j] = to_i8(f[k], 1024.0f);
    }
    *reinterpret_cast<uint4*>(w2q + (size_t)idx * 16) = q.u;
}

// ---------------- K1: LDS-free i8 frag-GEMM (K=64) + closed-form LIF -----------------
// Grid 2048 x 256 thr (4 waves, 64x64 out each). Per kt(K=64): 8 dwordx4 loads
// + 16 mfma_i32_16x16x64_i8; 16 iterations fully unrolled (compiler hoists loads).
// i1 = acc/32768 + b1. Masks in K2's K=64 fragment order (coalesced stores).
__global__ __launch_bounds__(256, 2) void k_gemm1_i8(
    const signed char* __restrict__ xf,
    const signed char* __restrict__ w1f,
    const float* __restrict__ b1,
    unsigned short* __restrict__ M16,
    unsigned char* __restrict__ M4,
    unsigned int* __restrict__ spike_count)
{
    __shared__ unsigned lutm[22];
    const int tid  = threadIdx.x;
    if (tid < 22) {
        unsigned m = 0;
        if (tid >= 1 && tid <= 20)
            for (int t = tid - 1; t < T_STEPS; t += tid) m |= 1u << t;
        lutm[tid] = m;
    }
    __syncthreads();

    const int wv   = tid >> 6;
    const int lane = tid & 63;
    const int l15  = lane & 15;
    const int g    = lane >> 4;
    const int wr   = wv >> 1;
    const int wc   = wv & 1;

    const int wg    = blockIdx.x;
    const int xcd   = wg & 7;
    const int local = wg >> 3;
    const int sc    = local >> 4;
    const int sl    = local & 15;
    const int b_panel = xcd * 16 + (sc >> 2) * 4 + (sl >> 2);
    const int h_idx   = (sc & 3) * 4 + (sl & 3);

    i32x4 acc[4][4];
    #pragma unroll
    for (int i = 0; i < 4; ++i)
        #pragma unroll
        for (int j = 0; j < 4; ++j)
            acc[i][j] = (i32x4){0, 0, 0, 0};

    const signed char* Ap = w1f + (size_t)h_idx * 131072 + wr * 4096 + lane * 16;
    const signed char* Bp = xf + (size_t)b_panel * 131072 + wc * 4096 + lane * 16;

    #pragma unroll
    for (int kt = 0; kt < 16; ++kt) {
        i32x4 A[4], Bv[4];
        #pragma unroll
        for (int m = 0; m < 4; ++m)
            A[m] = *reinterpret_cast<const i32x4*>(Ap + (size_t)kt * 8192 + m * 1024);
        #pragma unroll
        for (int n = 0; n < 4; ++n)
            Bv[n] = *reinterpret_cast<const i32x4*>(Bp + (size_t)kt * 8192 + n * 1024);
        #pragma unroll
        for (int m = 0; m < 4; ++m)
            #pragma unroll
            for (int n = 0; n < 4; ++n)
                acc[m][n] = __builtin_amdgcn_mfma_i32_16x16x64_i8(
                    A[m], Bv[n], acc[m][n], 0, 0, 0);
    }

    int spikes = 0;
    #pragma unroll
    for (int m = 0; m < 4; ++m) {
        const int h0l = h_idx * 128 + wr * 64 + m * 16 + g * 4;
        const int kt64 = h_idx * 2 + wr;
        const int k2lane = m * 16 + l15;
        float4 bias = *reinterpret_cast<const float4*>(b1 + h0l);
        float bj[4] = {bias.x, bias.y, bias.z, bias.w};
        #pragma unroll
        for (int n = 0; n < 4; ++n) {
            const int bt = b_panel * 8 + wc * 4 + n;
            unsigned mk[4];
            #pragma unroll
            for (int j = 0; j < 4; ++j) {
                float i1 = __fmul_rn((float)acc[m][n][j], 3.0517578125e-05f) + bj[j];
                float arg = fmaf(-0.1f, __builtin_amdgcn_rcpf(i1), 1.0f);
                float pf = ceilf(__log2f(arg) * -6.578813478960192f);
                int p = (int)pf;
                p = p < 1 ? 1 : (p > 21 ? 21 : p);
                unsigned mask = lutm[p];
                mk[j] = (i1 >= 0.113843485f) ? mask : 0u;
                spikes += __popc(mk[j]);
            }
            const size_t rec = ((size_t)bt * 32 + kt64) * 64 + k2lane;
            *reinterpret_cast<uint2*>(M16 + rec * 16 + g * 4) =
                make_uint2((mk[0] & 0xffffu) | (mk[1] << 16),
                           (mk[2] & 0xffffu) | (mk[3] << 16));
            *reinterpret_cast<unsigned int*>(M4 + rec * 16 + g * 4) =
                (mk[0] >> 16) | ((mk[1] >> 16) << 8) | ((mk[2] >> 16) << 16) | ((mk[3] >> 16) << 24);
        }
    }
    #pragma unroll
    for (int off = 32; off > 0; off >>= 1)
        spikes += __shfl_down(spikes, off);
    if (lane == 0)
        atomicAdd(spike_count, (unsigned int)spikes);
}

// ---------------- K2: layer 2 via i8 MFMA K=64, LDS-free main loop (unchanged) -------
__global__ __launch_bounds__(256, 2) void k_layer2_i8(
    const unsigned short* __restrict__ M16,
    const unsigned char* __restrict__ M4,
    const signed char* __restrict__ W2q,
    const float* __restrict__ b2,
    float* __restrict__ out)
{
    __shared__ __align__(16) float smem[5700];   // 16b x 16c (pad 17) x 21t
    const int tid  = threadIdx.x;
    const int tg   = tid >> 6;        // wave = t-group: t in [tg*5, tg*5+5)
    const int lane = tid & 63;
    const int l15  = lane & 15;
    const int g    = lane >> 4;
    const int b0   = blockIdx.x * 16;
    const int t0   = tg * 5;

    i32x4 acc[8][5];
    #pragma unroll
    for (int n = 0; n < 8; ++n)
        #pragma unroll
        for (int t = 0; t < 5; ++t)
            acc[n][t] = (i32x4){0, 0, 0, 0};

    const unsigned short* m16p = M16 + (size_t)blockIdx.x * 32768 + lane * 16;
    const unsigned char*  m4p  = M4  + (size_t)blockIdx.x * 32768 + lane * 16;
    const signed char*    fbase = W2q + (size_t)lane * 16;

    for (int kt = 0; kt < 32; ++kt) {
        const unsigned short* mp = m16p + (size_t)kt * 1024;
        uint4 wa = *reinterpret_cast<const uint4*>(mp);
        uint4 wb = *reinterpret_cast<const uint4*>(mp + 8);
        uint4 w4 = make_uint4(0u, 0u, 0u, 0u);
        if (tg == 3)
            w4 = *reinterpret_cast<const uint4*>(m4p + (size_t)kt * 1024);

        union { i32x4 v; unsigned u[4]; } A[5];
        #pragma unroll
        for (int tl = 0; tl < 5; ++tl) {
            const int t = t0 + tl;
            if (t < 16) {
                A[tl].u[0] = ((wa.x >> t) & 0x10001u) | (((wa.y >> t) & 0x10001u) << 8);
                A[tl].u[1] = ((wa.z >> t) & 0x10001u) | (((wa.w >> t) & 0x10001u) << 8);
                A[tl].u[2] = ((wb.x >> t) & 0x10001u) | (((wb.y >> t) & 0x10001u) << 8);
                A[tl].u[3] = ((wb.z >> t) & 0x10001u) | (((wb.w >> t) & 0x10001u) << 8);
            } else {
                const int tt = t - 16;
                A[tl].u[0] = __builtin_amdgcn_perm(0u, (w4.x >> tt) & 0x01010101u, 0x03010200u);
                A[tl].u[1] = __builtin_amdgcn_perm(0u, (w4.y >> tt) & 0x01010101u, 0x03010200u);
                A[tl].u[2] = __builtin_amdgcn_perm(0u, (w4.z >> tt) & 0x01010101u, 0x03010200u);
                A[tl].u[3] = __builtin_amdgcn_perm(0u, (w4.w >> tt) & 0x01010101u, 0x03010200u);
            }
        }

        const signed char* fk = fbase + (size_t)kt * 8192;
        i32x4 Bv[8];
        #pragma unroll
        for (int nt = 0; nt < 8; ++nt)
            Bv[nt] = *reinterpret_cast<const i32x4*>(fk + nt * 1024);
        #pragma unroll
        for (int tl = 0; tl < 5; ++tl)
            #pragma unroll
            for (int nt = 0; nt < 8; ++nt)
                acc[nt][tl] = __builtin_amdgcn_mfma_i32_16x16x64_i8(
                    A[tl].v, Bv[nt], acc[nt][tl], 0, 0, 0);
    }

    // epilogue: 8 chunks of 16 cols; transpose through LDS, then LIF per (b,c)
    #pragma unroll
    for (int q = 0; q < 8; ++q) {
        __syncthreads();
        #pragma unroll
        for (int tl = 0; tl < 5; ++tl)
            #pragma unroll
            for (int j = 0; j < 4; ++j)
                smem[((g * 4 + j) * 17 + l15) * 21 + (t0 + tl)] = (float)acc[q][tl][j];
        __syncthreads();
        {
            const int bl  = tid >> 4;     // 0..15
            const int c16 = tid & 15;
            const int c   = q * 16 + c16;
            const float bias = b2[c];
            float u2 = 0.0f; int cnt = 0;
            #pragma unroll
            for (int t = 0; t < T_STEPS; ++t) {
                float X = __fadd_rn(__fmul_rn(smem[(bl * 17 + c16) * 21 + t], 0.0009765625f), bias);
                u2 = __fadd_rn(__fmul_rn(0.9f, u2), X);
                if (u2 >= 1.0f) { cnt++; u2 = 0.0f; }
            }
            out[(size_t)(b0 + bl) * C_SZ + c] = (float)cnt / 20.0f;
        }
    }
}

// ---------------- K3: mean_spikes = total / (B * T) ----------------
__global__ void k_finalize(const unsigned int* __restrict__ spike_count, float* __restrict__ out) {
    out[(size_t)B_SZ * C_SZ] = (float)(*spike_count) / (float)((size_t)B_SZ * T_STEPS);
}

extern "C" void kernel_launch(void* const* d_in, const int* in_sizes, int n_in,
                              void* d_out, int out_size, void* d_ws, size_t ws_size,
                              hipStream_t stream) {
    const float* x  = (const float*)d_in[0];
    const float* W1 = (const float*)d_in[1];
    const float* b1 = (const float*)d_in[2];
    const float* W2 = (const float*)d_in[3];
    const float* b2 = (const float*)d_in[4];
    float* out = (float*)d_out;

    char* ws = (char*)d_ws;
    const size_t m16_b  = (size_t)B_SZ * H_SZ * 2;   // 67.1 MB
    const size_t m4_b   = (size_t)B_SZ * H_SZ;       // 33.6 MB
    const size_t xfi_b  = (size_t)B_SZ * D_SZ;       // 16.8 MB
    const size_t w1fi_b = (size_t)H_SZ * D_SZ;       //  2.1 MB
    const size_t w2q_b  = (size_t)C_SZ * H_SZ;       //  0.26 MB

    size_t off = 0;
    unsigned short* M16  = (unsigned short*)(ws + off); off += m16_b;
    unsigned char*  M4   = (unsigned char*)(ws + off);  off += m4_b;
    signed char*    xfi  = (signed char*)(ws + off);    off += xfi_b;
    signed char*    w1fi = (signed char*)(ws + off);    off += w1fi_b;
    signed char*    w2q  = (signed char*)(ws + off);    off += w2q_b;
    unsigned int* counter = (unsigned int*)(ws + off);  off += 256;

    hipMemsetAsync(counter, 0, sizeof(unsigned int), stream);

    k_w1fragi8<<<512, 256, 0, stream>>>(W1, w1fi);   // 131072 threads EXACT
    k_w2fragi8<<<64, 256, 0, stream>>>(W2, w2q);     // 16384 threads EXACT
    k_xfragi8<<<4096, 256, 0, stream>>>(x, xfi);     // 1048576 threads EXACT

    k_gemm1_i8<<<2048, 256, 0, stream>>>(xfi, w1fi, b1, M16, M4, counter);

    k_layer2_i8<<<B_SZ / 16, 256, 0, stream>>>(M16, M4, w2q, b2, out);

    k_finalize<<<1, 1, 0, stream>>>(counter, out);
}